// Round 12
// baseline (350.278 us; speedup 1.0000x reference)
//
#include <hip/hip_runtime.h>
#include <math.h>

#define NA 30
#define ND 435          // NA*(NA-1)/2
#define NI 90           // 3*NA
#define NP 12
#define NNB (NA-1)
#define SST 91          // S/Sp row stride (coprime to 32 banks)
#define NTHR 256

typedef float v2f __attribute__((ext_vector_type(2)));

struct Pre {
  int   pidx[NP][ND];      // pair permutation: d -> image pair under perm p
  int   sigma[NP][NA];     // atom permutation
  int   sigma_inv[NP][NA];
  int   rowv[ND];
  int   colv[ND];
  float rjp[NP][ND];       // R_desc[j][pidx[p][d]]
  float spj[NA][SST];      // expanded antisym S' of j: sign(a,u)*Rdj[pair(a,u)][c]
  // gtab[k][p][a]: d | su<<9 | u<<14   (coalesced in a; u = k+(k>=a), su = sigma_p(u))
  unsigned int gtab[NNB][NP][NA];
  // stab[a][a2][p]: u | sa<<5 | valid<<15  (u = sigma_inv[p][a2], sa = sigma[p][a])
  alignas(16) unsigned int stab[NA][NA][NP];
  unsigned int hmask[NA][NA];   // bit p set iff sigma_p(a)==a2
};

__device__ __forceinline__ int pair_index(int x, int y) {
  int hi = max(x, y), lo = min(x, y);
  return hi * (hi - 1) / 2 + lo;
}

// ---- preA: small dependent graph work, single block ----
__global__ void preA_kernel(const int* __restrict__ tpl, Pre* ws) {
  const int tid = threadIdx.x;
  const int nthr = blockDim.x;

  for (int d = tid; d < ND; d += nthr) {
    int a = (int)floorf((1.0f + sqrtf(1.0f + 8.0f * (float)d)) * 0.5f);
    while (a * (a - 1) / 2 > d) --a;
    while ((a + 1) * a / 2 <= d) ++a;
    ws->rowv[d] = a;
    ws->colv[d] = d - a * (a - 1) / 2;
  }
  for (int idx = tid; idx < NP * ND; idx += nthr) {
    int d = idx / NP, p = idx % NP;          // tpl layout: [d*NP + p]
    ws->pidx[p][d] = tpl[idx] - p * ND;
  }
  __syncthreads();
  // recover atom permutation sigma_p
  for (int idx = tid; idx < NP * NA; idx += nthr) {
    int p = idx / NA, a = idx % NA;
    int u1 = (a == 0) ? 1 : 0;
    int u2 = (a <= 1) ? 2 : 1;
    int e1 = ws->pidx[p][pair_index(a, u1)];
    int e2 = ws->pidx[p][pair_index(a, u2)];
    int r1 = ws->rowv[e1], c1 = ws->colv[e1];
    int r2 = ws->rowv[e2], c2 = ws->colv[e2];
    int sa = (r1 == r2 || r1 == c2) ? r1 : c1;
    ws->sigma[p][a] = sa;
  }
  __syncthreads();
  for (int idx = tid; idx < NP * NA; idx += nthr) {
    int p = idx / NA, a = idx % NA;
    ws->sigma_inv[p][ws->sigma[p][a]] = a;
  }
  __syncthreads();
  for (int it = tid; it < NA * NA; it += nthr) {
    int a = it / NA, a2 = it % NA;
    unsigned m = 0;
#pragma unroll
    for (int p = 0; p < NP; ++p)
      if (ws->sigma[p][a] == a2) m |= (1u << p);
    ws->hmask[a][a2] = m;
  }
}

// ---- preB: bulk table fills, grid-parallel ----
__global__ void preB_kernel(const float* __restrict__ R_desc,
                            const float* __restrict__ R_d_desc,
                            const int* __restrict__ jptr,
                            Pre* ws) {
  const int gid = blockIdx.x * blockDim.x + threadIdx.x;
  const int gsz = gridDim.x * blockDim.x;
  const int j = *jptr;

  for (int idx = gid; idx < NP * ND; idx += gsz) {
    int p = idx / ND, d = idx % ND;
    ws->rjp[p][d] = R_desc[(size_t)j * ND + ws->pidx[p][d]];
  }
  // expanded antisymmetric S' of point j, row stride SST
  for (int idx = gid; idx < NA * SST; idx += gsz) {
    int a = idx / SST, r = idx % SST;
    float val = 0.f;
    if (r < NI) {
      int u = r / 3, c = r % 3;
      if (u != a) {
        int d = pair_index(a, u);
        float t = R_d_desc[(size_t)j * (ND * 3) + 3 * d + c];
        val = (a > u) ? t : -t;
      }
    }
    ((float*)ws->spj)[idx] = val;
  }
  // gtab[k][p][a]
  for (int idx = gid; idx < NNB * NP * NA; idx += gsz) {
    int a = idx % NA;
    int r = idx / NA;
    int p = r % NP, k = r / NP;
    int u = k + (k >= a ? 1 : 0);
    int d = pair_index(a, u);
    int su = ws->sigma[p][u];
    ws->gtab[k][p][a] = (unsigned)d | ((unsigned)su << 9) | ((unsigned)u << 14);
  }
  // stab[a][a2][p]
  for (int idx = gid; idx < NA * NA * NP; idx += gsz) {
    int p = idx % NP;
    int r = idx / NP;
    int a2 = r % NA, a = r / NA;
    unsigned int v = 0;
    if (ws->sigma[p][a] != a2) {
      int u = ws->sigma_inv[p][a2];
      int sa = ws->sigma[p][a];
      v = (unsigned)u | ((unsigned)sa << 5) | (1u << 15);
    }
    ws->stab[a][a2][p] = v;
  }
}

__global__ __launch_bounds__(NTHR, 4) void gdml_kernel(
    const float* __restrict__ R_desc,
    const float* __restrict__ R_d_desc,
    const Pre* __restrict__ ws,
    float* __restrict__ out) {
  const int n = blockIdx.x;
  const int tid = threadIdx.x;

  __shared__ float rn_l[ND];                      // 1.74 KB
  __shared__ float S[NA * SST];                   // 10.92 KB expanded antisym Rdn (n)
  __shared__ float Sp[NA * SST];                  // 10.92 KB expanded antisym Rdj (j)
  __shared__ float v_s[NP * NI];                  // 4.32 KB
  __shared__ float w_s[NP * NI];                  // 4.32 KB
  __shared__ alignas(16) unsigned short HhU[NA * NP * 9];  // 6.48 KB bf16 heavy blocks
  __shared__ float dist2[NP];
  __shared__ float e_s[NP], e1_s[NP];
  // total ~38.8 KB -> 4 blocks/CU

  const float q   = 0.22360679774997896f;   // sqrt(5)/10
  const float qq3 = 0.016666666666666666f;  // q*q/3

  // ---- P0: coalesced loads; raw Rdn staged into HhU (dead until Hh stores) ----
  if (tid < NP) dist2[tid] = 0.f;
  for (int d = tid; d < ND; d += NTHR) rn_l[d] = R_desc[(size_t)n * ND + d];
  float* raw = (float*)HhU;   // 1305 floats fit in 3240 ushorts
  for (int i = tid; i < ND * 3; i += NTHR)
    raw[i] = R_d_desc[(size_t)n * (ND * 3) + i];
  for (int i = tid; i < NA * SST; i += NTHR)
    Sp[i] = ((const float*)ws->spj)[i];
  __syncthreads();

  // ---- P0b: build expanded sign-baked S from staged raw ----
  for (int i = tid; i < NA * NI; i += NTHR) {
    int a = i / NI, r = i % NI;
    int u = r / 3, c = r % 3;
    float val = 0.f;
    if (u != a) {
      int d = pair_index(a, u);
      float t = raw[3 * d + c];
      val = (a > u) ? t : -t;
    }
    S[a * SST + r] = val;
  }
  __syncthreads();

  // ---- P2: per (p,a): v, inner, heavy H (regs), dist partial ----
  auto p2_item = [&](int it, float (&h)[9]) {
    int a = it % NA, p = it / NA;
    int sa = (ws->stab[a][0][p] ? 0 : 0);   // placeholder to keep structure clear
    (void)sa;
    int sa2 = 0;
    {
      // sigma_p(a): recover from gtab of any neighbor? cheaper: read from global sigma
      sa2 = ws->sigma[p][a];
    }
    const float* Srow = S + a * SST;
    const float* Prow = Sp + sa2 * SST;
    const float* rjpp = &ws->rjp[p][0];
    v2f V01 = {0.f, 0.f}; float V2 = 0.f;
    v2f I01 = {0.f, 0.f}; float I2 = 0.f;
    v2f H0 = {0.f, 0.f}, H1 = {0.f, 0.f}, H2 = {0.f, 0.f};
    float Hc0 = 0.f, Hc1 = 0.f, Hc2 = 0.f;
    float xq = 0.f;
    for (int k = 0; k < NNB; ++k) {
      unsigned g = ws->gtab[k][p][a];
      int d  = g & 511;
      int su = (g >> 9) & 31;
      int u  = (g >> 14) & 31;
      float x = q * (rn_l[d] - rjpp[d]);
      xq += x * x;
      float s0 = Srow[3 * u], s1 = Srow[3 * u + 1], s2 = Srow[3 * u + 2];
      float t0 = Prow[3 * su], t1 = Prow[3 * su + 1], t2 = Prow[3 * su + 2];
      V01 += (v2f){x, x} * (v2f){s0, s1}; V2 += x * s2;
      I01 += (v2f){x, x} * (v2f){t0, t1}; I2 += x * t2;
      v2f t01 = {t0, t1};
      H0 += (v2f){s0, s0} * t01; Hc0 += s0 * t2;
      H1 += (v2f){s1, s1} * t01; Hc1 += s1 * t2;
      H2 += (v2f){s2, s2} * t01; Hc2 += s2 * t2;
    }
    v_s[p * NI + 3 * a + 0] = V01.x;   // unscaled; e applied later
    v_s[p * NI + 3 * a + 1] = V01.y;
    v_s[p * NI + 3 * a + 2] = V2;
    w_s[p * NI + 3 * sa2 + 0] = I01.x;
    w_s[p * NI + 3 * sa2 + 1] = I01.y;
    w_s[p * NI + 3 * sa2 + 2] = I2;
    atomicAdd(&dist2[p], xq);
    h[0] = H0.x; h[1] = H0.y; h[2] = Hc0;
    h[3] = H1.x; h[4] = H1.y; h[5] = Hc1;
    h[6] = H2.x; h[7] = H2.y; h[8] = Hc2;
  };

  float h1[9], h2[9];
  const int it1 = tid;
  const int it2 = tid + NTHR;
  const bool has2 = (it2 < NP * NA);
  p2_item(it1, h1);
  if (has2) p2_item(it2, h2);
  __syncthreads();   // b2: raw staging dead, dist2 complete, v/w visible

  if (tid < NP) {
    float dist = sqrtf(dist2[tid] * 0.5f);   // each d counted twice
    float e = expf(-dist) * qq3;
    e_s[tid] = e;
    e1_s[tid] = e * (1.f + dist);
  }
  {
    int a = it1 % NA, p = it1 / NA;
    unsigned short* hb = &HhU[(a * NP + p) * 9];
#pragma unroll
    for (int r = 0; r < 9; ++r) {
      unsigned bi = __float_as_uint(h1[r]);
      hb[r] = (unsigned short)((bi + 0x7FFFu + ((bi >> 16) & 1u)) >> 16);  // RNE bf16
    }
  }
  if (has2) {
    int a = it2 % NA, p = it2 / NA;
    unsigned short* hb = &HhU[(a * NP + p) * 9];
#pragma unroll
    for (int r = 0; r < 9; ++r) {
      unsigned bi = __float_as_uint(h2[r]);
      hb[r] = (unsigned short)((bi + 0x7FFFu + ((bi >> 16) & 1u)) >> 16);
    }
  }
  __syncthreads();   // b3: e/e1 + Hh visible

  // ---- scale v by e_p ----
  for (int i = tid; i < NP * NI; i += NTHR) v_s[i] *= e_s[i / NI];
  __syncthreads();   // b4

  // ---- P5: one thread per (a, a2, a2+15) pair of 3x3 blocks ----
  float e1r[NP];
#pragma unroll
  for (int p = 0; p < NP; ++p) e1r[p] = e1_s[p];

  float* outn = out + (size_t)n * (NI * NI);
  for (int itp = tid; itp < NA * 15; itp += NTHR) {
    int a = itp / 15, cc = itp % 15;
    int a2x = cc, a2y = cc + 15;
    const float* Srow = S + a * SST;
    v2f AX0 = {0.f,0.f}, AX1 = {0.f,0.f}, AX2 = {0.f,0.f};
    float BX0 = 0.f, BX1 = 0.f, BX2 = 0.f;
    v2f AY0 = {0.f,0.f}, AY1 = {0.f,0.f}, AY2 = {0.f,0.f};
    float BY0 = 0.f, BY1 = 0.f, BY2 = 0.f;
    const uint4* sx4 = (const uint4*)&ws->stab[a][a2x][0];
    const uint4* sy4 = (const uint4*)&ws->stab[a][a2y][0];
    uint4 xa = sx4[0], xb = sx4[1], xc = sx4[2];
    uint4 ya = sy4[0], yb = sy4[1], yc = sy4[2];
    unsigned svx[12] = {xa.x, xa.y, xa.z, xa.w, xb.x, xb.y, xb.z, xb.w,
                        xc.x, xc.y, xc.z, xc.w};
    unsigned svy[12] = {ya.x, ya.y, ya.z, ya.w, yb.x, yb.y, yb.z, yb.w,
                        yc.x, yc.y, yc.z, yc.w};
#pragma unroll
    for (int p = 0; p < NP; ++p) {
      float e1 = e1r[p];
      // shared v reads (broadcast) for both column blocks
      float v0 = v_s[p * NI + 3 * a + 0];
      float v1 = v_s[p * NI + 3 * a + 1];
      float v2v = v_s[p * NI + 3 * a + 2];
      // ---- column block X ----
      {
        float w0 = w_s[p * NI + 3 * a2x + 0];
        float w1 = w_s[p * NI + 3 * a2x + 1];
        float w2 = w_s[p * NI + 3 * a2x + 2];
        v2f w01 = {w0, w1};
        AX0 += (v2f){v0, v0} * w01;   BX0 += v0 * w2;
        AX1 += (v2f){v1, v1} * w01;   BX1 += v1 * w2;
        AX2 += (v2f){v2v, v2v} * w01; BX2 += v2v * w2;
        unsigned g = svx[p];
        float f = (g & 0x8000u) ? e1 : 0.f;
        int u  = g & 31;
        int sa = (g >> 5) & 31;
        float r0 = f * Srow[3 * u];
        float r1 = f * Srow[3 * u + 1];
        float r2 = f * Srow[3 * u + 2];
        float j0 = Sp[sa * SST + 3 * a2x + 0];
        float j1 = Sp[sa * SST + 3 * a2x + 1];
        float j2 = Sp[sa * SST + 3 * a2x + 2];
        v2f j01 = {j0, j1};
        AX0 += (v2f){r0, r0} * j01; BX0 += r0 * j2;
        AX1 += (v2f){r1, r1} * j01; BX1 += r1 * j2;
        AX2 += (v2f){r2, r2} * j01; BX2 += r2 * j2;
      }
      // ---- column block Y ----
      {
        float w0 = w_s[p * NI + 3 * a2y + 0];
        float w1 = w_s[p * NI + 3 * a2y + 1];
        float w2 = w_s[p * NI + 3 * a2y + 2];
        v2f w01 = {w0, w1};
        AY0 += (v2f){v0, v0} * w01;   BY0 += v0 * w2;
        AY1 += (v2f){v1, v1} * w01;   BY1 += v1 * w2;
        AY2 += (v2f){v2v, v2v} * w01; BY2 += v2v * w2;
        unsigned g = svy[p];
        float f = (g & 0x8000u) ? e1 : 0.f;
        int u  = g & 31;
        int sa = (g >> 5) & 31;
        float r0 = f * Srow[3 * u];
        float r1 = f * Srow[3 * u + 1];
        float r2 = f * Srow[3 * u + 2];
        float j0 = Sp[sa * SST + 3 * a2y + 0];
        float j1 = Sp[sa * SST + 3 * a2y + 1];
        float j2 = Sp[sa * SST + 3 * a2y + 2];
        v2f j01 = {j0, j1};
        AY0 += (v2f){r0, r0} * j01; BY0 += r0 * j2;
        AY1 += (v2f){r1, r1} * j01; BY1 += r1 * j2;
        AY2 += (v2f){r2, r2} * j01; BY2 += r2 * j2;
      }
    }
    unsigned m = ws->hmask[a][a2x];
    while (m) {
      int p = __ffs(m) - 1;
      m &= m - 1;
      float e1 = e1r[p];
      const unsigned short* hb = &HhU[(a * NP + p) * 9];
      float hf[9];
#pragma unroll
      for (int r = 0; r < 9; ++r) hf[r] = __uint_as_float((unsigned)hb[r] << 16);
      AX0 -= e1 * (v2f){hf[0], hf[1]}; BX0 -= e1 * hf[2];
      AX1 -= e1 * (v2f){hf[3], hf[4]}; BX1 -= e1 * hf[5];
      AX2 -= e1 * (v2f){hf[6], hf[7]}; BX2 -= e1 * hf[8];
    }
    m = ws->hmask[a][a2y];
    while (m) {
      int p = __ffs(m) - 1;
      m &= m - 1;
      float e1 = e1r[p];
      const unsigned short* hb = &HhU[(a * NP + p) * 9];
      float hf[9];
#pragma unroll
      for (int r = 0; r < 9; ++r) hf[r] = __uint_as_float((unsigned)hb[r] << 16);
      AY0 -= e1 * (v2f){hf[0], hf[1]}; BY0 -= e1 * hf[2];
      AY1 -= e1 * (v2f){hf[3], hf[4]}; BY1 -= e1 * hf[5];
      AY2 -= e1 * (v2f){hf[6], hf[7]}; BY2 -= e1 * hf[8];
    }
    float* ob = outn + (size_t)(3 * a) * NI + 3 * a2x;
    ob[0] = AX0.x;  ob[1] = AX0.y;  ob[2] = BX0;
    ob[45] = AY0.x; ob[46] = AY0.y; ob[47] = BY0;
    ob[NI + 0] = AX1.x;  ob[NI + 1] = AX1.y;  ob[NI + 2] = BX1;
    ob[NI + 45] = AY1.x; ob[NI + 46] = AY1.y; ob[NI + 47] = BY1;
    ob[2 * NI + 0] = AX2.x;  ob[2 * NI + 1] = AX2.y;  ob[2 * NI + 2] = BX2;
    ob[2 * NI + 45] = AY2.x; ob[2 * NI + 46] = AY2.y; ob[2 * NI + 47] = BY2;
  }
}

extern "C" void kernel_launch(void* const* d_in, const int* in_sizes, int n_in,
                              void* d_out, int out_size, void* d_ws, size_t ws_size,
                              hipStream_t stream) {
  const float* R_desc   = (const float*)d_in[0];
  const float* R_d_desc = (const float*)d_in[1];
  const int*   tpl      = (const int*)d_in[2];
  const int*   jptr     = (const int*)d_in[3];
  float* out = (float*)d_out;
  Pre* ws = (Pre*)d_ws;

  const int n_train = in_sizes[0] / ND;

  hipLaunchKernelGGL(preA_kernel, dim3(1), dim3(256), 0, stream, tpl, ws);
  hipLaunchKernelGGL(preB_kernel, dim3(48), dim3(256), 0, stream,
                     R_desc, R_d_desc, jptr, ws);
  hipLaunchKernelGGL(gdml_kernel, dim3(n_train), dim3(NTHR), 0, stream,
                     R_desc, R_d_desc, ws, out);
}

// Round 13
// 89.361 us; speedup vs baseline: 3.9198x; 3.9198x over previous
//
#include <hip/hip_runtime.h>
#include <math.h>

#define NA 30
#define ND 435          // NA*(NA-1)/2
#define NI 90           // 3*NA
#define NP 12
#define NNB (NA-1)

typedef float v2f __attribute__((ext_vector_type(2)));

struct Pre {
  int   pidx[NP][ND];      // pair permutation: d -> image pair under perm p
  int   sigma[NP][NA];     // atom permutation
  int   sigma_inv[NP][NA];
  int   rowv[ND];
  int   colv[ND];
  float rjp[NP][ND];       // R_desc[j][pidx[p][d]]
  alignas(16) float spj[NA][NI];  // expanded antisym S' of point j: sign(a,u)*Rdj[pair(a,u)][c]
  // gtab[k][p][a]: d | su<<9 | s1<<14      (coalesced in a; u = k+(k>=a), su = sigma_p(u), s1 = a>u)
  unsigned int gtab[NNB][NP][NA];
  // stab[a][a2][p]: d1 | sa<<9 | s1<<14 | valid<<15
  alignas(16) unsigned int stab[NA][NA][NP];
  unsigned int hmask[NA][NA];   // bit p set iff sigma_p(a)==a2
};

__device__ __forceinline__ int pair_index(int x, int y) {
  int hi = max(x, y), lo = min(x, y);
  return hi * (hi - 1) / 2 + lo;
}

// ---- preA: small dependent graph work, single block ----
__global__ void preA_kernel(const int* __restrict__ tpl, Pre* ws) {
  const int tid = threadIdx.x;
  const int nthr = blockDim.x;

  for (int d = tid; d < ND; d += nthr) {
    int a = (int)floorf((1.0f + sqrtf(1.0f + 8.0f * (float)d)) * 0.5f);
    while (a * (a - 1) / 2 > d) --a;
    while ((a + 1) * a / 2 <= d) ++a;
    ws->rowv[d] = a;
    ws->colv[d] = d - a * (a - 1) / 2;
  }
  for (int idx = tid; idx < NP * ND; idx += nthr) {
    int d = idx / NP, p = idx % NP;          // tpl layout: [d*NP + p]
    ws->pidx[p][d] = tpl[idx] - p * ND;
  }
  __syncthreads();
  // recover atom permutation sigma_p
  for (int idx = tid; idx < NP * NA; idx += nthr) {
    int p = idx / NA, a = idx % NA;
    int u1 = (a == 0) ? 1 : 0;
    int u2 = (a <= 1) ? 2 : 1;
    int e1 = ws->pidx[p][pair_index(a, u1)];
    int e2 = ws->pidx[p][pair_index(a, u2)];
    int r1 = ws->rowv[e1], c1 = ws->colv[e1];
    int r2 = ws->rowv[e2], c2 = ws->colv[e2];
    int sa = (r1 == r2 || r1 == c2) ? r1 : c1;
    ws->sigma[p][a] = sa;
  }
  __syncthreads();
  for (int idx = tid; idx < NP * NA; idx += nthr) {
    int p = idx / NA, a = idx % NA;
    ws->sigma_inv[p][ws->sigma[p][a]] = a;
  }
  __syncthreads();
  for (int it = tid; it < NA * NA; it += nthr) {
    int a = it / NA, a2 = it % NA;
    unsigned m = 0;
#pragma unroll
    for (int p = 0; p < NP; ++p)
      if (ws->sigma[p][a] == a2) m |= (1u << p);
    ws->hmask[a][a2] = m;
  }
}

// ---- preB: bulk table fills, grid-parallel ----
__global__ void preB_kernel(const float* __restrict__ R_desc,
                            const float* __restrict__ R_d_desc,
                            const int* __restrict__ jptr,
                            Pre* ws) {
  const int gid = blockIdx.x * blockDim.x + threadIdx.x;
  const int gsz = gridDim.x * blockDim.x;
  const int j = *jptr;

  for (int idx = gid; idx < NP * ND; idx += gsz) {
    int p = idx / ND, d = idx % ND;
    ws->rjp[p][d] = R_desc[(size_t)j * ND + ws->pidx[p][d]];
  }
  // expanded antisymmetric S' of point j
  for (int idx = gid; idx < NA * NI; idx += gsz) {
    int a = idx / NI, r = idx % NI;
    int u = r / 3, c = r % 3;
    float val = 0.f;
    if (u != a) {
      int d = pair_index(a, u);
      float t = R_d_desc[(size_t)j * (ND * 3) + 3 * d + c];
      val = (a > u) ? t : -t;
    }
    ((float*)ws->spj)[idx] = val;
  }
  // gtab[k][p][a]
  for (int idx = gid; idx < NNB * NP * NA; idx += gsz) {
    int a = idx % NA;
    int r = idx / NA;
    int p = r % NP, k = r / NP;
    int u = k + (k >= a ? 1 : 0);
    int d = pair_index(a, u);
    int su = ws->sigma[p][u];
    unsigned g = (unsigned)d | ((unsigned)su << 9);
    if (a > u) g |= (1u << 14);
    ws->gtab[k][p][a] = g;
  }
  // stab[a][a2][p]
  for (int idx = gid; idx < NA * NA * NP; idx += gsz) {
    int p = idx % NP;
    int r = idx / NP;
    int a2 = r % NA, a = r / NA;
    unsigned int v = 0;
    if (ws->sigma[p][a] != a2) {
      int u = ws->sigma_inv[p][a2];
      int d1 = pair_index(a, u);
      int sa = ws->sigma[p][a];
      v = (unsigned)d1 | ((unsigned)sa << 9) | (1u << 15);
      if (a > u) v |= (1u << 14);
    }
    ws->stab[a][a2][p] = v;
  }
}

__global__ __launch_bounds__(256, 4) void gdml_kernel(
    const float* __restrict__ R_desc,
    const float* __restrict__ R_d_desc,
    const Pre* __restrict__ ws,
    float* __restrict__ out) {
  const int n = blockIdx.x;
  const int tid = threadIdx.x;

  __shared__ float rn_l[ND];          // 1.74 KB  R_desc[n]
  __shared__ float Rdn_l[ND * 3];     // 5.22 KB  R_d_desc[n]
  __shared__ alignas(16) float Sp[NA * NI];  // 10.8 KB expanded antisym Rdj (point j)
  __shared__ float v_s[NP * NI];      // 4.32 KB
  __shared__ float w_s[NP * NI];      // 4.32 KB
  __shared__ float Hh[NA * NP * 9];   // 12.96 KB heavy 3x3 blocks
  __shared__ float dist2[NP];
  __shared__ float e_s[NP], e1_s[NP];
  // total ~38.6 KB -> 4 blocks/CU

  const float q   = 0.22360679774997896f;   // sqrt(5)/10
  const float qq3 = 0.016666666666666666f;  // q*q/3

  // ---- P0: coalesced fills ----
  if (tid < NP) dist2[tid] = 0.f;
  for (int d = tid; d < ND; d += 256) rn_l[d] = R_desc[(size_t)n * ND + d];
  for (int i = tid; i < ND * 3; i += 256)
    Rdn_l[i] = R_d_desc[(size_t)n * (ND * 3) + i];
  {
    const float4* g4 = (const float4*)ws->spj;
    float4* s4 = (float4*)Sp;
    for (int i = tid; i < (NA * NI) / 4; i += 256) s4[i] = g4[i];
  }
  __syncthreads();

  // ---- P2: per (p,a): v, inner, heavy H (regs), dist partial ----
  auto p2_item = [&](int it, float (&h)[9]) {
    int a = it % NA, p = it / NA;
    int sa = ws->sigma[p][a];
    const float* Prow = Sp + sa * NI;
    const float* rjpp = &ws->rjp[p][0];
    v2f V01 = {0.f, 0.f}; float V2 = 0.f;
    v2f I01 = {0.f, 0.f}; float I2 = 0.f;
    v2f H0 = {0.f, 0.f}, H1 = {0.f, 0.f}, H2 = {0.f, 0.f};
    float Hc0 = 0.f, Hc1 = 0.f, Hc2 = 0.f;
    float xq = 0.f;
    for (int k = 0; k < NNB; ++k) {
      unsigned g = ws->gtab[k][p][a];
      int d  = g & 511;
      int su = (g >> 9) & 31;
      float s1 = (g & (1u << 14)) ? 1.f : -1.f;
      float x = q * (rn_l[d] - rjpp[d]);
      xq += x * x;
      float n0 = Rdn_l[3 * d], n1 = Rdn_l[3 * d + 1], n2 = Rdn_l[3 * d + 2];
      float t0 = Prow[3 * su], t1 = Prow[3 * su + 1], t2 = Prow[3 * su + 2];
      float sx = s1 * x;
      float sn0 = s1 * n0, sn1 = s1 * n1, sn2 = s1 * n2;
      V01 += (v2f){sx, sx} * (v2f){n0, n1}; V2 += sx * n2;
      I01 += (v2f){x, x} * (v2f){t0, t1};   I2 += x * t2;
      v2f t01 = {t0, t1};
      H0 += (v2f){sn0, sn0} * t01; Hc0 += sn0 * t2;
      H1 += (v2f){sn1, sn1} * t01; Hc1 += sn1 * t2;
      H2 += (v2f){sn2, sn2} * t01; Hc2 += sn2 * t2;
    }
    v_s[p * NI + 3 * a + 0] = V01.x;   // unscaled; e applied later
    v_s[p * NI + 3 * a + 1] = V01.y;
    v_s[p * NI + 3 * a + 2] = V2;
    w_s[p * NI + 3 * sa + 0] = I01.x;
    w_s[p * NI + 3 * sa + 1] = I01.y;
    w_s[p * NI + 3 * sa + 2] = I2;
    atomicAdd(&dist2[p], xq);
    h[0] = H0.x; h[1] = H0.y; h[2] = Hc0;
    h[3] = H1.x; h[4] = H1.y; h[5] = Hc1;
    h[6] = H2.x; h[7] = H2.y; h[8] = Hc2;
  };

  float h1[9], h2[9];
  const int it1 = tid;
  const int it2 = tid + 256;
  const bool has2 = (it2 < NP * NA);
  p2_item(it1, h1);
  if (has2) p2_item(it2, h2);
  __syncthreads();

  // ---- e/e1 (each (p,d) counted twice in dist2) + Hh stores ----
  if (tid < NP) {
    float dist = sqrtf(dist2[tid] * 0.5f);
    float e = expf(-dist) * qq3;
    e_s[tid] = e;
    e1_s[tid] = e * (1.f + dist);
  }
  {
    int a = it1 % NA, p = it1 / NA;
    float* hb = &Hh[(a * NP + p) * 9];
#pragma unroll
    for (int r = 0; r < 9; ++r) hb[r] = h1[r];
  }
  if (has2) {
    int a = it2 % NA, p = it2 / NA;
    float* hb = &Hh[(a * NP + p) * 9];
#pragma unroll
    for (int r = 0; r < 9; ++r) hb[r] = h2[r];
  }
  __syncthreads();

  // ---- scale v by e_p ----
  for (int i = tid; i < NP * NI; i += 256) v_s[i] *= e_s[i / NI];
  __syncthreads();

  // ---- P5: fused output, one thread per (a,a2) 3x3 block ----
  float e1r[NP];
#pragma unroll
  for (int p = 0; p < NP; ++p) e1r[p] = e1_s[p];

  float* outn = out + (size_t)n * (NI * NI);
  for (int it = tid; it < NA * NA; it += 256) {
    int a = it / NA, a2 = it % NA;
    v2f A0 = {0.f, 0.f}, A1 = {0.f, 0.f}, A2 = {0.f, 0.f};
    float B0 = 0.f, B1 = 0.f, B2 = 0.f;
    const uint4* st4 = (const uint4*)&ws->stab[a][a2][0];
    uint4 ua = st4[0], ub = st4[1], uc = st4[2];
    unsigned stv[12] = {ua.x, ua.y, ua.z, ua.w, ub.x, ub.y, ub.z, ub.w,
                        uc.x, uc.y, uc.z, uc.w};
#pragma unroll
    for (int p = 0; p < NP; ++p) {
      // rank-12 part: v broadcast, w stride-3 (conflict-free)
      float v0 = v_s[p * NI + 3 * a + 0];
      float v1 = v_s[p * NI + 3 * a + 1];
      float v2v = v_s[p * NI + 3 * a + 2];
      float w0 = w_s[p * NI + 3 * a2 + 0];
      float w1 = w_s[p * NI + 3 * a2 + 1];
      float w2 = w_s[p * NI + 3 * a2 + 2];
      v2f w01 = {w0, w1};
      A0 += (v2f){v0, v0} * w01;   B0 += v0 * w2;
      A1 += (v2f){v1, v1} * w01;   B1 += v1 * w2;
      A2 += (v2f){v2v, v2v} * w01; B2 += v2v * w2;
      // single-term: +e1p*s1 * Rdn[d1] (x) Sp[sa][a2]
      unsigned g = stv[p];
      float e1 = e1r[p];
      float fs = (g & (1u << 15)) ? ((g & (1u << 14)) ? e1 : -e1) : 0.f;
      int d1 = g & 511;
      int sa = (g >> 9) & 31;
      float r0 = fs * Rdn_l[3 * d1];
      float r1 = fs * Rdn_l[3 * d1 + 1];
      float r2 = fs * Rdn_l[3 * d1 + 2];
      float j0 = Sp[sa * NI + 3 * a2 + 0];
      float j1 = Sp[sa * NI + 3 * a2 + 1];
      float j2 = Sp[sa * NI + 3 * a2 + 2];
      v2f j01 = {j0, j1};
      A0 += (v2f){r0, r0} * j01; B0 += r0 * j2;
      A1 += (v2f){r1, r1} * j01; B1 += r1 * j2;
      A2 += (v2f){r2, r2} * j01; B2 += r2 * j2;
    }
    unsigned m = ws->hmask[a][a2];
    while (m) {
      int p = __ffs(m) - 1;
      m &= m - 1;
      float e1 = e1r[p];
      const float* hb = &Hh[(a * NP + p) * 9];
      A0 -= e1 * (v2f){hb[0], hb[1]}; B0 -= e1 * hb[2];
      A1 -= e1 * (v2f){hb[3], hb[4]}; B1 -= e1 * hb[5];
      A2 -= e1 * (v2f){hb[6], hb[7]}; B2 -= e1 * hb[8];
    }
    float* ob = outn + (size_t)(3 * a) * NI + 3 * a2;
    ob[0] = A0.x;          ob[1] = A0.y;          ob[2] = B0;
    ob[NI + 0] = A1.x;     ob[NI + 1] = A1.y;     ob[NI + 2] = B1;
    ob[2 * NI + 0] = A2.x; ob[2 * NI + 1] = A2.y; ob[2 * NI + 2] = B2;
  }
}

extern "C" void kernel_launch(void* const* d_in, const int* in_sizes, int n_in,
                              void* d_out, int out_size, void* d_ws, size_t ws_size,
                              hipStream_t stream) {
  const float* R_desc   = (const float*)d_in[0];
  const float* R_d_desc = (const float*)d_in[1];
  const int*   tpl      = (const int*)d_in[2];
  const int*   jptr     = (const int*)d_in[3];
  float* out = (float*)d_out;
  Pre* ws = (Pre*)d_ws;

  const int n_train = in_sizes[0] / ND;

  hipLaunchKernelGGL(preA_kernel, dim3(1), dim3(256), 0, stream, tpl, ws);
  hipLaunchKernelGGL(preB_kernel, dim3(48), dim3(256), 0, stream,
                     R_desc, R_d_desc, jptr, ws);
  hipLaunchKernelGGL(gdml_kernel, dim3(n_train), dim3(256), 0, stream,
                     R_desc, R_d_desc, ws, out);
}